// Round 5
// baseline (302.346 us; speedup 1.0000x reference)
//
#include <hip/hip_runtime.h>

// SSIM (7x7 uniform window) over B=64, C=1, H=W=384 fp32 images.
// out = mean over interior 378x378 crop of all 64 images (scalar).
//
// 2 dispatches only:
//  K1 max_kernel: 256 block-maxes of gt -> ws_bmax[256] (plain stores),
//     block 0 also zero-inits ws_sum / ws_cnt (read only by next dispatch).
//  K2 ssim_kernel: prologue reduces ws_bmax; fused separable box-filter SSIM
//     (R2 structure: 128-thr blocks, scalar register ring, VGPR~44);
//     double accumulation; last-block finalize -> d_out[0].

#define PADW 3
#define BW 128            // output columns per block (= blockDim.x)
#define BAND 22           // output rows per block
#define NCHUNK 4          // NIN = 28 staged rows (4 chunks of 7)
#define NIN 28

constexpr int B_ = 64, H_ = 384, W_ = 384;
constexpr int OUTD = W_ - 2 * PADW;                       // 378
constexpr int NBANDS = (OUTD + BAND - 1) / BAND;          // 18
constexpr int NTILES = 3;
constexpr int TOTAL_BLOCKS = NTILES * NBANDS * B_;        // 3456
constexpr int NMAXBLK = 256;
constexpr double NPIX = (double)B_ * OUTD * OUTD;         // 9,144,576

__global__ void __launch_bounds__(256)
max_kernel(const float4* __restrict__ g4, float* __restrict__ bmax,
           double* ws_sum, unsigned* ws_cnt, int n4) {
    const int t = threadIdx.x;
    int tid = blockIdx.x * 256 + t;
    float m = -3.402823466e38f;
    for (int i = tid; i < n4; i += 256 * NMAXBLK) {
        float4 v = g4[i];
        m = fmaxf(m, fmaxf(fmaxf(v.x, v.y), fmaxf(v.z, v.w)));
    }
#pragma unroll
    for (int off = 32; off > 0; off >>= 1)
        m = fmaxf(m, __shfl_down(m, off));
    __shared__ float sm[4];
    if ((t & 63) == 0) sm[t >> 6] = m;
    __syncthreads();
    if (t == 0) {
        bmax[blockIdx.x] = fmaxf(fmaxf(sm[0], sm[1]), fmaxf(sm[2], sm[3]));
        if (blockIdx.x == 0) { *ws_sum = 0.0; *ws_cnt = 0u; }  // read only by K2
    }
}

__device__ __forceinline__ float ssim_px(float sx, float sy, float sxx, float syy, float sxy,
                                         float C1, float C2) {
    const float inv49 = 1.0f / 49.0f;
    const float covn  = 49.0f / 48.0f;
    float ux  = sx * inv49, uy = sy * inv49;
    float uxx = sxx * inv49 - ux * ux;
    float uyy = syy * inv49 - uy * uy;
    float uxy = sxy * inv49 - ux * uy;
    float vvx = covn * uxx, vvy = covn * uyy, vvxy = covn * uxy;
    float num = (2.0f * ux * uy + C1) * (2.0f * vvxy + C2);
    float den = (ux * ux + uy * uy + C1) * (vvx + vvy + C2);
    return num * __builtin_amdgcn_rcpf(den);   // ~1 ulp; fine vs 1e-4 threshold on mean
}

__global__ void __launch_bounds__(BW)
ssim_kernel(const float* __restrict__ gt, const float* __restrict__ pred,
            const float* __restrict__ bmax, double* ws_sum, unsigned* ws_cnt,
            float* __restrict__ out) {
    const int t    = threadIdx.x;
    const int tile = blockIdx.x;   // 0..2 column tiles
    const int band = blockIdx.y;   // 0..NBANDS-1 row bands
    const int b    = blockIdx.z;   // 0..63 images

    __shared__ float sg[7][BW + 6];
    __shared__ float sp[7][BW + 6];
    __shared__ float smax[2];
    __shared__ double sred[2];

    // ---- prologue: reduce the 256 block-maxes (redundant per block, ~0.2us)
    float m = fmaxf(bmax[t], bmax[t + BW]);
#pragma unroll
    for (int off = 32; off > 0; off >>= 1)
        m = fmaxf(m, __shfl_down(m, off));
    if ((t & 63) == 0) smax[t >> 6] = m;
    __syncthreads();
    const float dr = fmaxf(smax[0], smax[1]);
    const float C1 = (0.01f * dr) * (0.01f * dr);
    const float C2 = (0.03f * dr) * (0.03f * dr);

    const int w0    = PADW + tile * BW;          // first output col of tile
    const int cb    = w0 - PADW;                 // first input col
    const int extra = min(BW + 6, W_ - cb) - BW; // 6 (tiles 0,1) or 0 (tile 2)
    const int row0  = band * BAND;               // first input row / output row idx
    const int wcol  = w0 + t;                    // this thread's output column
    const bool active = (wcol <= W_ - 1 - PADW); // cols 3..380 are valid outputs

    // vertical ring of horizontal 7-tap sums, in REGISTERS
    float rx[7], ry[7], rxx[7], ryy[7], rxy[7];
#pragma unroll
    for (int j = 0; j < 7; ++j) { rx[j]=0.f; ry[j]=0.f; rxx[j]=0.f; ryy[j]=0.f; rxy[j]=0.f; }

    float vx = 0.f, vy = 0.f, vxx = 0.f, vyy = 0.f, vxy = 0.f;
    double acc = 0.0;

    const float* gbase = gt   + (size_t)b * H_ * W_;
    const float* pbase = pred + (size_t)b * H_ * W_;

    for (int c = 0; c < NCHUNK; ++c) {
        const int base_ir = row0 + c * 7;
        __syncthreads();   // protect previous chunk's sg/sp reads
#pragma unroll
        for (int j = 0; j < 7; ++j) {
            const int ir = min(base_ir + j, H_ - 1);
            const float* gr = gbase + (size_t)ir * W_ + cb;
            const float* pr = pbase + (size_t)ir * W_ + cb;
            sg[j][t] = gr[t];
            sp[j][t] = pr[t];
            if (t < 6) {
                sg[j][BW + t] = (t < extra) ? gr[BW + t] : 0.0f;
                sp[j][BW + t] = (t < extra) ? pr[BW + t] : 0.0f;
            }
        }
        __syncthreads();

#pragma unroll
        for (int j = 0; j < 7; ++j) {
            float hx = 0.f, hy = 0.f, hxx = 0.f, hyy = 0.f, hxy = 0.f;
#pragma unroll
            for (int k = 0; k < 7; ++k) {
                float g = sg[j][t + k], p = sp[j][t + k];
                hx += g; hy += p;
                hxx = fmaf(g, g, hxx);
                hyy = fmaf(p, p, hyy);
                hxy = fmaf(g, p, hxy);
            }
            vx  += hx  - rx[j];   rx[j]  = hx;
            vy  += hy  - ry[j];   ry[j]  = hy;
            vxx += hxx - rxx[j];  rxx[j] = hxx;
            vyy += hyy - ryy[j];  ryy[j] = hyy;
            vxy += hxy - rxy[j];  rxy[j] = hxy;

            const int i = c * 7 + j;
            if (i >= 6) {
                const int orow = row0 + i - 6;
                if (active && orow < OUTD) {
                    acc += (double)ssim_px(vx, vy, vxx, vyy, vxy, C1, C2);
                }
            }
        }
    }

    // block reduction (double) -> one f64 atomic per block; last block finalizes
#pragma unroll
    for (int off = 32; off > 0; off >>= 1)
        acc += __shfl_down(acc, off);
    if ((t & 63) == 0) sred[t >> 6] = acc;
    __syncthreads();
    if (t == 0) {
        atomicAdd(ws_sum, sred[0] + sred[1]);
        __threadfence();
        unsigned prev = atomicAdd(ws_cnt, 1u);
        if (prev == (unsigned)(TOTAL_BLOCKS - 1)) {
            double tot = atomicAdd(ws_sum, 0.0);   // coherent read-back
            out[0] = (float)(tot / NPIX);
        }
    }
}

extern "C" void kernel_launch(void* const* d_in, const int* in_sizes, int n_in,
                              void* d_out, int out_size, void* d_ws, size_t ws_size,
                              hipStream_t stream) {
    const float* gt   = (const float*)d_in[0];
    const float* pred = (const float*)d_in[1];
    // d_in[2] is the uniform 1/49 window -> constant-folded into the kernel.
    float* out = (float*)d_out;

    double*   ws_sum  = (double*)d_ws;                     // offset 0
    unsigned* ws_cnt  = (unsigned*)((char*)d_ws + 8);      // offset 8
    float*    ws_bmax = (float*)((char*)d_ws + 16);        // offset 16, 256 floats

    const int n4 = B_ * H_ * W_ / 4;  // 2,359,296 float4s
    max_kernel<<<NMAXBLK, 256, 0, stream>>>((const float4*)gt, ws_bmax, ws_sum, ws_cnt, n4);

    dim3 grid(NTILES, NBANDS, B_);    // col tiles x row bands x images
    ssim_kernel<<<grid, BW, 0, stream>>>(gt, pred, ws_bmax, ws_sum, ws_cnt, out);
}

// Round 6
// 184.470 us; speedup vs baseline: 1.6390x; 1.6390x over previous
//
#include <hip/hip_runtime.h>

// SSIM (7x7 uniform window) over B=64, C=1, H=W=384 fp32 images.
// out = mean over interior 378x378 crop of all 64 images (scalar).
//
// R2 structure (proven 62us ssim) + ONE change: software-pipelined staging
// (register prefetch of next 7-row chunk + double-buffered LDS tile).
//
// Kernel 1: max(gt)            -> ws[0] (monotone-encoded uint)
// Kernel 2: fused separable box-filter SSIM, register vertical ring
// Kernel 3: scalar finalize    -> d_out[0]

#define PADW 3
#define BW 128            // output columns per block (= blockDim.x)
#define BAND 36           // output rows per block
#define NIN (BAND + 6)    // input rows per block (42 = 6 chunks of 7)
#define NCHUNK (NIN / 7)

constexpr int B_ = 64, H_ = 384, W_ = 384;
constexpr int OUTD = W_ - 2 * PADW;                       // 378
constexpr int NBANDS = (OUTD + BAND - 1) / BAND;          // 11
constexpr double NPIX = (double)B_ * OUTD * OUTD;         // 9,144,576

// monotone float->uint mapping so uint atomicMax == float max (handles sign)
__device__ __forceinline__ unsigned enc_f(float f) {
    unsigned u = __float_as_uint(f);
    return (u & 0x80000000u) ? ~u : (u | 0x80000000u);
}
__device__ __forceinline__ float dec_f(unsigned e) {
    return __uint_as_float((e & 0x80000000u) ? (e & 0x7fffffffu) : ~e);
}

__global__ void __launch_bounds__(256)
max_kernel(const float4* __restrict__ g4, unsigned* ws_max, int n4) {
    int tid = blockIdx.x * blockDim.x + threadIdx.x;
    int stride = gridDim.x * blockDim.x;
    float m = -3.402823466e38f;
    for (int i = tid; i < n4; i += stride) {
        float4 v = g4[i];
        m = fmaxf(m, fmaxf(fmaxf(v.x, v.y), fmaxf(v.z, v.w)));
    }
#pragma unroll
    for (int off = 32; off > 0; off >>= 1)
        m = fmaxf(m, __shfl_down(m, off));
    __shared__ float sm[4];
    if ((threadIdx.x & 63) == 0) sm[threadIdx.x >> 6] = m;
    __syncthreads();
    if (threadIdx.x == 0) {
        float mm = fmaxf(fmaxf(sm[0], sm[1]), fmaxf(sm[2], sm[3]));
        atomicMax(ws_max, enc_f(mm));
    }
}

__global__ void __launch_bounds__(BW)
ssim_kernel(const float* __restrict__ gt, const float* __restrict__ pred,
            const unsigned* __restrict__ ws_max, double* ws_sum) {
    const int t    = threadIdx.x;
    const int tile = blockIdx.x;   // 0..2 column tiles
    const int band = blockIdx.y;   // 0..NBANDS-1 row bands
    const int b    = blockIdx.z;   // 0..63 images

    const float dr     = dec_f(*ws_max);
    const float C1     = (0.01f * dr) * (0.01f * dr);
    const float C2     = (0.03f * dr) * (0.03f * dr);
    const float inv49  = 1.0f / 49.0f;
    const float covn   = 49.0f / 48.0f;

    const int w0    = PADW + tile * BW;          // first output col of tile
    const int cb    = w0 - PADW;                 // first input col
    const int extra = min(BW + 6, W_ - cb) - BW; // 6 (tiles 0,1) or 0 (tile 2)
    const int row0  = band * BAND;               // first input row / output row idx
    const int wcol  = w0 + t;                    // this thread's output column
    const bool active = (wcol <= W_ - 1 - PADW); // cols 3..380 are valid outputs

    __shared__ float sg[2][7][BW + 6];           // double-buffered staging tile
    __shared__ float sp[2][7][BW + 6];
    __shared__ double sred[2];

    // vertical ring of horizontal 7-tap sums, in REGISTERS
    float rx[7], ry[7], rxx[7], ryy[7], rxy[7];
#pragma unroll
    for (int j = 0; j < 7; ++j) { rx[j]=0.f; ry[j]=0.f; rxx[j]=0.f; ryy[j]=0.f; rxy[j]=0.f; }

    float vx = 0.f, vy = 0.f, vxx = 0.f, vyy = 0.f, vxy = 0.f;
    double acc = 0.0;

    const float* gbase = gt   + (size_t)b * H_ * W_;
    const float* pbase = pred + (size_t)b * H_ * W_;

    // chunk prefetch registers (7 rows x {gt,pred}, plus 6-col tail for t<6)
    float pgv[7], ppv[7], tgv[7], tpv[7];

    auto prefetch = [&](int c) {
        const int base_ir = row0 + c * 7;
#pragma unroll
        for (int j = 0; j < 7; ++j) {
            const int ir = min(base_ir + j, H_ - 1);
            const float* gr = gbase + (size_t)ir * W_ + cb;
            const float* pr = pbase + (size_t)ir * W_ + cb;
            pgv[j] = gr[t];
            ppv[j] = pr[t];
            if (t < 6) {
                tgv[j] = (t < extra) ? gr[BW + t] : 0.0f;
                tpv[j] = (t < extra) ? pr[BW + t] : 0.0f;
            }
        }
    };
    auto commit = [&](int buf) {
#pragma unroll
        for (int j = 0; j < 7; ++j) {
            sg[buf][j][t] = pgv[j];
            sp[buf][j][t] = ppv[j];
            if (t < 6) {
                sg[buf][j][BW + t] = tgv[j];
                sp[buf][j][BW + t] = tpv[j];
            }
        }
    };

    prefetch(0);
    commit(0);
    __syncthreads();

    for (int c = 0; c < NCHUNK; ++c) {
        if (c + 1 < NCHUNK) prefetch(c + 1);    // issue global loads early
        const int buf = c & 1;

#pragma unroll
        for (int j = 0; j < 7; ++j) {
            float hx = 0.f, hy = 0.f, hxx = 0.f, hyy = 0.f, hxy = 0.f;
#pragma unroll
            for (int k = 0; k < 7; ++k) {
                float g = sg[buf][j][t + k], p = sp[buf][j][t + k];
                hx += g; hy += p;
                hxx = fmaf(g, g, hxx);
                hyy = fmaf(p, p, hyy);
                hxy = fmaf(g, p, hxy);
            }
            vx  += hx  - rx[j];   rx[j]  = hx;
            vy  += hy  - ry[j];   ry[j]  = hy;
            vxx += hxx - rxx[j];  rxx[j] = hxx;
            vyy += hyy - ryy[j];  ryy[j] = hyy;
            vxy += hxy - rxy[j];  rxy[j] = hxy;

            const int i = c * 7 + j;
            if (i >= 6) {
                const int orow = row0 + i - 6;
                if (active && orow < OUTD) {
                    float ux  = vx * inv49, uy = vy * inv49;
                    float uxx = vxx * inv49 - ux * ux;
                    float uyy = vyy * inv49 - uy * uy;
                    float uxy = vxy * inv49 - ux * uy;
                    float vvx = covn * uxx, vvy = covn * uyy, vvxy = covn * uxy;
                    float num = (2.0f * ux * uy + C1) * (2.0f * vvxy + C2);
                    float den = (ux * ux + uy * uy + C1) * (vvx + vvy + C2);
                    acc += (double)(num / den);
                }
            }
        }

        if (c + 1 < NCHUNK) {
            commit((c + 1) & 1);   // other buffer: no pre-barrier needed
            __syncthreads();       // publish before next iteration's reads
        }
    }

    // block reduction (double) -> one f64 atomic per block
#pragma unroll
    for (int off = 32; off > 0; off >>= 1)
        acc += __shfl_down(acc, off);
    if ((t & 63) == 0) sred[t >> 6] = acc;
    __syncthreads();
    if (t == 0) atomicAdd(ws_sum, sred[0] + sred[1]);
}

__global__ void final_kernel(const double* __restrict__ ws_sum, float* __restrict__ out) {
    out[0] = (float)(ws_sum[0] / NPIX);
}

extern "C" void kernel_launch(void* const* d_in, const int* in_sizes, int n_in,
                              void* d_out, int out_size, void* d_ws, size_t ws_size,
                              hipStream_t stream) {
    const float* gt   = (const float*)d_in[0];
    const float* pred = (const float*)d_in[1];
    // d_in[2] is the uniform 1/49 window -> constant-folded into the kernel.
    float* out = (float*)d_out;

    unsigned* ws_max = (unsigned*)d_ws;
    double*   ws_sum = (double*)((char*)d_ws + 8);

    hipMemsetAsync(d_ws, 0, 16, stream);

    const int n4 = B_ * H_ * W_ / 4;  // 2,359,296 float4s
    max_kernel<<<1024, 256, 0, stream>>>((const float4*)gt, ws_max, n4);

    dim3 grid(3, NBANDS, 64);         // col tiles x row bands x images
    ssim_kernel<<<grid, BW, 0, stream>>>(gt, pred, ws_max, ws_sum);

    final_kernel<<<1, 1, 0, stream>>>(ws_sum, out);
}

// Round 7
// 158.109 us; speedup vs baseline: 1.9123x; 1.1667x over previous
//
#include <hip/hip_runtime.h>

// SSIM (7x7 uniform window) over B=64, C=1, H=W=384 fp32 images.
// out = mean over interior 378x378 crop of all 64 images (scalar).
//
// R4 tap scheme (float2, 2 cols/thread, 4 LDS instr/px) with R4's two defects
// removed: NO VGPR cap (launch_bounds min-waves arg) and NO per-block
// __threadfence/atomic finalize (per-block partial -> ws_part[], reduced by a
// separate final_kernel; dispatch boundary provides ordering).
//
// K1 max_kernel: max(gt) -> ws_max (monotone-encoded uint, atomicMax)
// K2 ssim_kernel: 64-thr single-wave blocks, 3 col tiles x 26 bands x 64 imgs
// K3 final_kernel: sum 4992 partials, divide, store d_out[0]

#define PADW 3
#define BT 64             // threads per block (1 wave); 63 compute 2 cols each
#define BAND 15           // output rows per block
#define NCHUNK 3          // NIN = 21 staged rows

constexpr int B_ = 64, H_ = 384, W_ = 384;
constexpr int W2 = W_ / 2;                                // row length in float2
constexpr int OUTD = W_ - 2 * PADW;                       // 378
constexpr int NBANDS = (OUTD + BAND - 1) / BAND;          // 26
constexpr int NTILES = 3;                                 // 3 x 126 cols = 378
constexpr int TOTAL_BLOCKS = NTILES * NBANDS * B_;        // 4992
constexpr double NPIX = (double)B_ * OUTD * OUTD;         // 9,144,576

__device__ __forceinline__ unsigned enc_f(float f) {
    unsigned u = __float_as_uint(f);
    return (u & 0x80000000u) ? ~u : (u | 0x80000000u);
}
__device__ __forceinline__ float dec_f(unsigned e) {
    return __uint_as_float((e & 0x80000000u) ? (e & 0x7fffffffu) : ~e);
}

__device__ __forceinline__ float2 f2add(float2 a, float2 b) { return make_float2(a.x + b.x, a.y + b.y); }
__device__ __forceinline__ float2 f2sub(float2 a, float2 b) { return make_float2(a.x - b.x, a.y - b.y); }

__global__ void __launch_bounds__(256)
max_kernel(const float4* __restrict__ g4, unsigned* ws_max, int n4) {
    int tid = blockIdx.x * blockDim.x + threadIdx.x;
    int stride = gridDim.x * blockDim.x;
    float m = -3.402823466e38f;
    for (int i = tid; i < n4; i += stride) {
        float4 v = g4[i];
        m = fmaxf(m, fmaxf(fmaxf(v.x, v.y), fmaxf(v.z, v.w)));
    }
#pragma unroll
    for (int off = 32; off > 0; off >>= 1)
        m = fmaxf(m, __shfl_down(m, off));
    __shared__ float sm[4];
    if ((threadIdx.x & 63) == 0) sm[threadIdx.x >> 6] = m;
    __syncthreads();
    if (threadIdx.x == 0) {
        float mm = fmaxf(fmaxf(sm[0], sm[1]), fmaxf(sm[2], sm[3]));
        atomicMax(ws_max, enc_f(mm));
    }
}

__device__ __forceinline__ float ssim_px(float sx, float sy, float sxx, float syy, float sxy,
                                         float C1, float C2) {
    const float inv49 = 1.0f / 49.0f;
    const float covn  = 49.0f / 48.0f;
    float ux  = sx * inv49, uy = sy * inv49;
    float uxx = sxx * inv49 - ux * ux;
    float uyy = syy * inv49 - uy * uy;
    float uxy = sxy * inv49 - ux * uy;
    float vvx = covn * uxx, vvy = covn * uyy, vvxy = covn * uxy;
    float num = (2.0f * ux * uy + C1) * (2.0f * vvxy + C2);
    float den = (ux * ux + uy * uy + C1) * (vvx + vvy + C2);
    return num / den;
}

__global__ void __launch_bounds__(BT)
ssim_kernel(const float* __restrict__ gt, const float* __restrict__ pred,
            const unsigned* __restrict__ ws_max, double* __restrict__ ws_part) {
    const int t    = threadIdx.x;
    const int tile = blockIdx.x;   // 0..2 column tiles (126 out cols each)
    const int band = blockIdx.y;   // 0..NBANDS-1
    const int b    = blockIdx.z;   // 0..63 images
    const int bid  = (b * NBANDS + band) * NTILES + tile;

    const float dr = dec_f(*ws_max);
    const float C1 = (0.01f * dr) * (0.01f * dr);
    const float C2 = (0.03f * dr) * (0.03f * dr);

    const int  row0   = band * BAND;
    const int  cbase2 = tile * 63;            // staged base, in float2 units
    const bool active = (t < 63);             // thread t -> out cols tile*126+3+2t, +1

    // 66 staged float2 per row; pad to 68 so sg[j][t+3] at t=63 stays in-array
    __shared__ float2 sg[7][68];
    __shared__ float2 sp[7][68];

    // vertical ring of horizontal 7-tap sums (2 columns packed in float2)
    float2 rx[7], ry[7], rxx[7], ryy[7], rxy[7];
#pragma unroll
    for (int j = 0; j < 7; ++j) {
        rx[j] = make_float2(0.f, 0.f); ry[j] = rx[j];
        rxx[j] = rx[j]; ryy[j] = rx[j]; rxy[j] = rx[j];
    }
    float2 vx = make_float2(0.f, 0.f), vy = vx, vxx = vx, vyy = vx, vxy = vx;
    double acc = 0.0;

    const float2* gbase = (const float2*)(gt   + (size_t)b * H_ * W_);
    const float2* pbase = (const float2*)(pred + (size_t)b * H_ * W_);

    for (int c = 0; c < NCHUNK; ++c) {
        __syncthreads();   // single-wave block: cheap
#pragma unroll
        for (int j = 0; j < 7; ++j) {
            const int ir = min(row0 + c * 7 + j, H_ - 1);
            const float2* gr = gbase + (size_t)ir * W2 + cbase2;
            const float2* pr = pbase + (size_t)ir * W2 + cbase2;
            sg[j][t] = gr[t];
            sp[j][t] = pr[t];
            if (t < 2) {                        // tail: elements 64, 65
                sg[j][64 + t] = gr[64 + t];
                sp[j][64 + t] = pr[64 + t];
            }
        }
        __syncthreads();

#pragma unroll
        for (int j = 0; j < 7; ++j) {
            // 8 taps (4 float2) covering both columns' 7-tap windows
            float2 d0 = sg[j][t], d1 = sg[j][t + 1], d2 = sg[j][t + 2], d3 = sg[j][t + 3];
            float2 e0 = sp[j][t], e1 = sp[j][t + 1], e2 = sp[j][t + 2], e3 = sp[j][t + 3];

            float hx0 = d0.x + d0.y + d1.x + d1.y + d2.x + d2.y + d3.x;
            float hy0 = e0.x + e0.y + e1.x + e1.y + e2.x + e2.y + e3.x;
            float hxx0 = fmaf(d0.x, d0.x, fmaf(d0.y, d0.y, fmaf(d1.x, d1.x,
                         fmaf(d1.y, d1.y, fmaf(d2.x, d2.x, fmaf(d2.y, d2.y, d3.x * d3.x))))));
            float hyy0 = fmaf(e0.x, e0.x, fmaf(e0.y, e0.y, fmaf(e1.x, e1.x,
                         fmaf(e1.y, e1.y, fmaf(e2.x, e2.x, fmaf(e2.y, e2.y, e3.x * e3.x))))));
            float hxy0 = fmaf(d0.x, e0.x, fmaf(d0.y, e0.y, fmaf(d1.x, e1.x,
                         fmaf(d1.y, e1.y, fmaf(d2.x, e2.x, fmaf(d2.y, e2.y, d3.x * e3.x))))));

            // horizontal slide for the second column: -tap0 +tap7
            float2 h_x  = make_float2(hx0,  hx0  - d0.x        + d3.y);
            float2 h_y  = make_float2(hy0,  hy0  - e0.x        + e3.y);
            float2 h_xx = make_float2(hxx0, hxx0 - d0.x * d0.x + d3.y * d3.y);
            float2 h_yy = make_float2(hyy0, hyy0 - e0.x * e0.x + e3.y * e3.y);
            float2 h_xy = make_float2(hxy0, hxy0 - d0.x * e0.x + d3.y * e3.y);

            // vertical sliding window: evict slot j, insert new row
            vx  = f2add(vx,  f2sub(h_x,  rx[j]));  rx[j]  = h_x;
            vy  = f2add(vy,  f2sub(h_y,  ry[j]));  ry[j]  = h_y;
            vxx = f2add(vxx, f2sub(h_xx, rxx[j])); rxx[j] = h_xx;
            vyy = f2add(vyy, f2sub(h_yy, ryy[j])); ryy[j] = h_yy;
            vxy = f2add(vxy, f2sub(h_xy, rxy[j])); rxy[j] = h_xy;

            const int i = c * 7 + j;
            if (i >= 6) {
                const int orow = row0 + i - 6;
                if (active && orow < OUTD) {
                    acc += (double)ssim_px(vx.x, vy.x, vxx.x, vyy.x, vxy.x, C1, C2)
                         + (double)ssim_px(vx.y, vy.y, vxx.y, vyy.y, vxy.y, C1, C2);
                }
            }
        }
    }

    // single-wave reduction (double) -> one plain store per block (no atomics)
#pragma unroll
    for (int off = 32; off > 0; off >>= 1)
        acc += __shfl_down(acc, off);
    if (t == 0) ws_part[bid] = acc;
}

__global__ void __launch_bounds__(256)
final_kernel(const double* __restrict__ ws_part, float* __restrict__ out) {
    const int t = threadIdx.x;
    double s = 0.0;
    for (int i = t; i < TOTAL_BLOCKS; i += 256) s += ws_part[i];
#pragma unroll
    for (int off = 32; off > 0; off >>= 1)
        s += __shfl_down(s, off);
    __shared__ double sd[4];
    if ((t & 63) == 0) sd[t >> 6] = s;
    __syncthreads();
    if (t == 0) out[0] = (float)((sd[0] + sd[1] + sd[2] + sd[3]) / NPIX);
}

extern "C" void kernel_launch(void* const* d_in, const int* in_sizes, int n_in,
                              void* d_out, int out_size, void* d_ws, size_t ws_size,
                              hipStream_t stream) {
    const float* gt   = (const float*)d_in[0];
    const float* pred = (const float*)d_in[1];
    // d_in[2] is the uniform 1/49 window -> constant-folded into the kernel.
    float* out = (float*)d_out;

    unsigned* ws_max  = (unsigned*)d_ws;                   // offset 0 (4 B)
    double*   ws_part = (double*)((char*)d_ws + 64);       // 4992 doubles (~39 KB)

    hipMemsetAsync(d_ws, 0, 64, stream);   // clear ws_max only; ws_part fully written

    const int n4 = B_ * H_ * W_ / 4;  // 2,359,296 float4s
    max_kernel<<<1024, 256, 0, stream>>>((const float4*)gt, ws_max, n4);

    dim3 grid(NTILES, NBANDS, B_);    // col tiles x row bands x images
    ssim_kernel<<<grid, BT, 0, stream>>>(gt, pred, ws_max, ws_part);

    final_kernel<<<1, 256, 0, stream>>>(ws_part, out);
}